// Round 4
// baseline (24288.406 us; speedup 1.0000x reference)
//
#include <hip/hip_runtime.h>
#include <math.h>

#define N_NODES 100000
#define N_GRAPHS 100
#define N_EDGES 1000000
#define H 256
#define L_POS 512
#define CH_T 25000    // transform/scatter node-chunk (4 chunks)
#define CH_G 8192     // GRU node-chunk (13 chunks)

// ---------------- zero fill (float4) ----------------
__global__ void zero_kernel(float4* __restrict__ p, int n4)
{
    int i = blockIdx.x * 256 + threadIdx.x;
    if (i < n4) p[i] = make_float4(0.f, 0.f, 0.f, 0.f);
}

// ---------------- init h: h = embed[tok] + pe[min(pos,512)] ----------------
__global__ void init_h_kernel(const int* __restrict__ nodes,
                              const float* __restrict__ embed,
                              float* __restrict__ h)
{
    int n = blockIdx.x;
    int j = threadIdx.x;
    int tok = nodes[n];
    int p = nodes[N_NODES + n];
    if (p > L_POS) p = L_POS;
    float pe = 0.0f;
    if (p > 0) {
        float pos = (float)(p - 1);
        float denom = powf(10000.0f, 2.0f * (float)j / (float)H);
        float ang = pos / denom;
        pe = (j & 1) ? cosf(ang) : sinf(ang);
    }
    h[(size_t)n * H + j] = embed[(size_t)tok * H + j] + pe;
}

// ---- tiled matmul: C(nrows x ncols, stride ldc) = A(nrows x 256, stride 256) @ B(256 x ncols, stride ldb) + bias [+C]
__global__ __launch_bounds__(256) void matmul_kernel(
    const float* __restrict__ A, const float* __restrict__ B,
    const float* __restrict__ bias, float* __restrict__ C,
    int nrows, int ncols, int ldb, int ldc, int accumulate)
{
    __shared__ float As[16][68];   // [k][m], padded
    __shared__ float Bs[16][64];   // [k][n]
    int bm = blockIdx.y << 6;
    int bn = blockIdx.x << 6;
    int tid = threadIdx.x;
    int tx = tid & 15, ty = tid >> 4;
    int a_row = tid >> 2;          // 0..63
    int a_k   = (tid & 3) << 2;    // 0,4,8,12
    int b_k   = tid >> 4;          // 0..15
    int b_col = (tid & 15) << 2;   // 0..60
    int grow = bm + a_row;
    bool a_ok = grow < nrows;
    const float* Aptr = A + (size_t)grow * 256;

    float acc[4][4];
    #pragma unroll
    for (int i = 0; i < 4; i++)
        #pragma unroll
        for (int j = 0; j < 4; j++) acc[i][j] = 0.0f;

    for (int k0 = 0; k0 < 256; k0 += 16) {
        float4 av = a_ok ? *(const float4*)(Aptr + k0 + a_k) : make_float4(0.f, 0.f, 0.f, 0.f);
        float4 bv = *(const float4*)(B + (size_t)(k0 + b_k) * ldb + bn + b_col);
        if (k0) __syncthreads();
        As[a_k + 0][a_row] = av.x;
        As[a_k + 1][a_row] = av.y;
        As[a_k + 2][a_row] = av.z;
        As[a_k + 3][a_row] = av.w;
        *(float4*)(&Bs[b_k][b_col]) = bv;
        __syncthreads();
        #pragma unroll
        for (int kk = 0; kk < 16; kk++) {
            float a0 = As[kk][(ty << 2) + 0];
            float a1 = As[kk][(ty << 2) + 1];
            float a2 = As[kk][(ty << 2) + 2];
            float a3 = As[kk][(ty << 2) + 3];
            float b0 = Bs[kk][(tx << 2) + 0];
            float b1 = Bs[kk][(tx << 2) + 1];
            float b2 = Bs[kk][(tx << 2) + 2];
            float b3 = Bs[kk][(tx << 2) + 3];
            acc[0][0] += a0 * b0; acc[0][1] += a0 * b1; acc[0][2] += a0 * b2; acc[0][3] += a0 * b3;
            acc[1][0] += a1 * b0; acc[1][1] += a1 * b1; acc[1][2] += a1 * b2; acc[1][3] += a1 * b3;
            acc[2][0] += a2 * b0; acc[2][1] += a2 * b1; acc[2][2] += a2 * b2; acc[2][3] += a2 * b3;
            acc[3][0] += a3 * b0; acc[3][1] += a3 * b1; acc[3][2] += a3 * b2; acc[3][3] += a3 * b3;
        }
    }

    #pragma unroll
    for (int i = 0; i < 4; i++) {
        int row = bm + (ty << 2) + i;
        if (row >= nrows) break;
        float* Crow = C + (size_t)row * ldc + bn + (tx << 2);
        #pragma unroll
        for (int j = 0; j < 4; j++) {
            float v = acc[i][j] + bias[bn + (tx << 2) + j];
            if (accumulate) v += Crow[j];
            Crow[j] = v;
        }
    }
}

// ---- edge scatter for a src-chunk: msgs[tgt] += transCh[src-c0] where etype==t && src in [c0,c1)
__global__ __launch_bounds__(256) void scatter_kernel(const int* __restrict__ edges,
                                                      const float* __restrict__ transCh,
                                                      float* __restrict__ msgs,
                                                      int t, int c0, int c1)
{
    int tid = blockIdx.x * 256 + threadIdx.x;
    int e = tid >> 6;
    if (e >= N_EDGES) return;
    if (edges[e * 3] != t) return;
    int src = edges[e * 3 + 1];
    if (src < c0 || src >= c1) return;
    int tgt = edges[e * 3 + 2];
    int c = (tid & 63) << 2;
    const float4 v = *(const float4*)(transCh + (size_t)(src - c0) * H + c);
    float* dst = msgs + (size_t)tgt * H + c;
    atomicAdd(dst + 0, v.x);
    atomicAdd(dst + 1, v.y);
    atomicAdd(dst + 2, v.z);
    atomicAdd(dst + 3, v.w);
}

// ---- GRU elementwise for a row chunk. Sch rows: [z|r|xh] (768); HHch rows: hh (256). h in place.
__global__ void gru_kernel(float* __restrict__ h, const float* __restrict__ S,
                           const float* __restrict__ HH, int r0, int nrows)
{
    int nl = blockIdx.x;
    if (nl >= nrows) return;
    int j = threadIdx.x;
    int n = r0 + nl;
    const float* Srow = S + (size_t)nl * 768;
    float sz = Srow[j];
    float sr = Srow[256 + j];
    float xh = Srow[512 + j];
    float hh = HH[(size_t)nl * 256 + j];
    size_t idx = (size_t)n * 256 + j;
    float hv = h[idx];
    float z = 1.0f / (1.0f + expf(-sz));
    float r = 1.0f / (1.0f + expf(-sr));
    float cand = tanhf(xh + r * hh);
    h[idx] = z * hv + (1.0f - z) * cand;
}

// ---------------- gate logits: g[n] = h[n] . gate_W + gate_b (wave per node) ----------------
__global__ __launch_bounds__(256) void gate_kernel(const float* __restrict__ h,
                                                   const float* __restrict__ gW,
                                                   const float* __restrict__ gb,
                                                   float* __restrict__ g)
{
    int tid = blockIdx.x * 256 + threadIdx.x;
    int n = tid >> 6;
    if (n >= N_NODES) return;
    int lane = tid & 63;
    float s = 0.0f;
    #pragma unroll
    for (int j = 0; j < 4; j++)
        s += h[(size_t)n * H + lane + j * 64] * gW[lane + j * 64];
    #pragma unroll
    for (int off = 32; off > 0; off >>= 1)
        s += __shfl_down(s, off);
    if (lane == 0) g[n] = s + gb[0];
}

// ---------------- per-graph softmax-gated readout (block per graph) ----------------
__global__ __launch_bounds__(256) void out_kernel(const float* __restrict__ h,
                                                  const float* __restrict__ g,
                                                  const int* __restrict__ sizes,
                                                  const float* __restrict__ outW,
                                                  const float* __restrict__ outB,
                                                  float* __restrict__ out)
{
    __shared__ float red[256];
    int gid = blockIdx.x;
    int tid = threadIdx.x;

    int start = 0, end = 0;
    {
        int c = 0;
        for (int i = 0; i < N_GRAPHS; i++) {
            int sz = sizes[i];
            if (i == gid) { start = c; end = c + sz; }
            c += sz;
        }
    }

    float m = -INFINITY;
    for (int n = start + tid; n < end; n += 256) m = fmaxf(m, g[n]);
    red[tid] = m; __syncthreads();
    for (int s = 128; s > 0; s >>= 1) {
        if (tid < s) red[tid] = fmaxf(red[tid], red[tid + s]);
        __syncthreads();
    }
    m = red[0]; __syncthreads();

    float s_ = 0.0f;
    for (int n = start + tid; n < end; n += 256) s_ += expf(g[n] - m);
    red[tid] = s_; __syncthreads();
    for (int s = 128; s > 0; s >>= 1) {
        if (tid < s) red[tid] += red[tid + s];
        __syncthreads();
    }
    float ssum = red[0]; __syncthreads();

    float acc = 0.0f;
    for (int n = start; n < end; n++) {
        float e = expf(g[n] - m);
        acc += e * h[(size_t)n * H + tid];
    }

    float inv = 1.0f / (ssum + 1e-16f);
    for (int c = 0; c < 2; c++) {
        red[tid] = acc * outW[tid * 2 + c];
        __syncthreads();
        for (int s = 128; s > 0; s >>= 1) {
            if (tid < s) red[tid] += red[tid + s];
            __syncthreads();
        }
        if (tid == 0) out[gid * 2 + c] = red[0] * inv + outB[c] * (ssum * inv);
        __syncthreads();
    }
}

extern "C" void kernel_launch(void* const* d_in, const int* in_sizes, int n_in,
                              void* d_out, int out_size, void* d_ws, size_t ws_size,
                              hipStream_t stream)
{
    const int*   nodes  = (const int*)d_in[0];
    const int*   gsizes = (const int*)d_in[1];
    const int*   edges  = (const int*)d_in[2];
    const float* embed  = (const float*)d_in[3];
    const float* type_w = (const float*)d_in[4];
    const float* type_b = (const float*)d_in[5];
    const float* gru_W  = (const float*)d_in[6];
    const float* gru_U  = (const float*)d_in[7];
    const float* gru_bi = (const float*)d_in[8];
    const float* gru_br = (const float*)d_in[9];
    const float* gate_W = (const float*)d_in[10];
    const float* gate_b = (const float*)d_in[11];
    const float* out_W  = (const float*)d_in[12];
    const float* out_b  = (const float*)d_in[13];
    float* out = (float*)d_out;

    // ---- workspace layout (floats) ----
    size_t NH  = (size_t)N_NODES * H;                       // 25.6M
    size_t SCR1 = (size_t)CH_T * H;                         // 6.4M  (transform chunk)
    size_t SCR2 = (size_t)CH_G * 768 + (size_t)CH_G * H;    // 8.39M (Sch + HHch)
    size_t SCR  = SCR1 > SCR2 ? SCR1 : SCR2;
    size_t need_floats = 2 * NH + SCR + N_NODES;
    // ~238.7 MB. If the harness scratch is smaller, bail out cleanly:
    // output stays zero -> test fails with absmax ~= max|ref| (~4.5e2), NOT a crash.
    if (ws_size < need_floats * sizeof(float)) return;

    float* ws      = (float*)d_ws;
    float* h       = ws;                 // N*H
    float* msgs    = h + NH;             // N*H
    float* scratch = msgs + NH;          // SCR (time-shared)
    float* g       = scratch + SCR;      // N

    float* transCh = scratch;            // CH_T*256  (message phase)
    float* Sch     = scratch;            // CH_G*768  (GRU phase)
    float* HHch    = scratch + (size_t)CH_G * 768;  // CH_G*256

    init_h_kernel<<<N_NODES, H, 0, stream>>>(nodes, embed, h);

    const int steps[2] = {3, 1};
    for (int l = 0; l < 2; l++) {
        const float* W  = gru_W  + (size_t)l * H * 768;
        const float* U  = gru_U  + (size_t)l * H * 768;
        const float* bi = gru_bi + (size_t)l * 768;
        const float* br = gru_br + (size_t)l * 768;
        for (int s = 0; s < steps[l]; s++) {
            // msgs = 0
            {
                int n4 = (int)(NH / 4);
                zero_kernel<<<(n4 + 255) / 256, 256, 0, stream>>>((float4*)msgs, n4);
            }
            // message passing: node chunks x 4 types; transform chunk then scatter its edges
            for (int c0 = 0; c0 < N_NODES; c0 += CH_T) {
                int nr = N_NODES - c0 < CH_T ? N_NODES - c0 : CH_T;
                for (int t = 0; t < 4; t++) {
                    const float* Wt = type_w + (size_t)(l * 4 + t) * H * H;
                    const float* bt = type_b + (size_t)(l * 4 + t) * H;
                    dim3 grid(H / 64, (nr + 63) / 64);
                    matmul_kernel<<<grid, 256, 0, stream>>>(h + (size_t)c0 * H, Wt, bt,
                                                            transCh, nr, H, H, H, 0);
                    scatter_kernel<<<(N_EDGES * 64) / 256, 256, 0, stream>>>(
                        edges, transCh, msgs, t, c0, c0 + nr);
                }
            }
            // GRU in row chunks (Sch = msgs@W+bi (+ h@U_zr+br_zr); HHch = h@U_h+br_h)
            for (int r0 = 0; r0 < N_NODES; r0 += CH_G) {
                int nr = N_NODES - r0 < CH_G ? N_NODES - r0 : CH_G;
                dim3 gridS(768 / 64, (nr + 63) / 64);
                matmul_kernel<<<gridS, 256, 0, stream>>>(msgs + (size_t)r0 * H, W, bi, Sch,
                                                         nr, 768, 768, 768, 0);
                dim3 gridU(512 / 64, (nr + 63) / 64);
                matmul_kernel<<<gridU, 256, 0, stream>>>(h + (size_t)r0 * H, U, br, Sch,
                                                         nr, 512, 768, 768, 1);
                dim3 gridH(256 / 64, (nr + 63) / 64);
                matmul_kernel<<<gridH, 256, 0, stream>>>(h + (size_t)r0 * H, U + 512, br + 512,
                                                         HHch, nr, 256, 768, 256, 0);
                gru_kernel<<<nr, 256, 0, stream>>>(h, Sch, HHch, r0, nr);
            }
        }
    }

    gate_kernel<<<(N_NODES * 64) / 256, 256, 0, stream>>>(h, gate_W, gate_b, g);
    out_kernel<<<N_GRAPHS, 256, 0, stream>>>(h, g, gsizes, out_W, out_b, out);
}